// Round 7
// baseline (233.675 us; speedup 1.0000x reference)
//
#include <hip/hip_runtime.h>
#include <hip/hip_bf16.h>

#define HH 512
#define WW 512
#define NPIX (HH * WW)
#define KTOP 64
#define NBINS2 1024
#define HSHIFT 15
#define NS 32
#define SLAB_ROWS 16
#define CAP2 2048
#define SELCAP 512
#define NMAPS (8 * 19)

static constexpr unsigned MINB = 0x3DCCCCCDu; // bits of 0.1f

__constant__ int KPT_A[19] = {1,1,2,3,5,6,1,8,9,1,11,12,1,0,14,0,15,2,5};
__constant__ int KPT_B[19] = {2,5,3,4,6,7,8,9,10,11,12,13,0,14,16,15,17,16,17};
__constant__ int PAF_X[19] = {12,20,14,16,22,24,0,2,4,6,8,10,28,30,34,32,36,18,26};
__constant__ int PAF_Y[19] = {13,21,15,17,23,25,1,3,5,7,9,11,29,31,35,33,37,19,27};

// key = (value bits << 32) | ~idx  -> rank by key DESC == (value desc, idx asc)
__device__ __forceinline__ unsigned long long mkkey(unsigned bits, unsigned idx) {
    return ((unsigned long long)bits << 32) | (unsigned long long)(~idx);
}

// Pass 1: per-slab (16 rows) exact top-64 peaks. Single global scan with
// histogram + full candidate capture; wave-ballot compaction avoids the
// same-address LDS-atomic serialization (one atomic per wave, not per lane).
__global__ __launch_bounds__(256) void peaks_slab_kernel(
    const float* __restrict__ hm_all,
    unsigned long long* __restrict__ candWs, unsigned* __restrict__ cntWs)
{
    const int slab = blockIdx.x;
    const int map  = blockIdx.y;
    const float* __restrict__ hm = hm_all + (size_t)map * NPIX;
    const int r0 = slab * SLAB_ROWS;
    const int tid = threadIdx.x;
    const int lane = tid & 63;

    __shared__ unsigned hist[NBINS2];
    __shared__ unsigned long long allK[CAP2];
    __shared__ unsigned long long selK[SELCAP];
    __shared__ unsigned chunkSum[256];
    __shared__ unsigned s_cnt, s_sel, s_thr;
    __shared__ unsigned long long topK[KTOP];

    for (int i = tid; i < NBINS2; i += 256) hist[i] = 0u;
    if (tid == 0) { s_cnt = 0u; s_sel = 0u; }
    if (tid < KTOP) topK[tid] = 0ull;
    __syncthreads();

    // scan: float4-vectorized, coalesced. Histogram + capture every peak key.
    for (int c = tid; c < SLAB_ROWS * 128; c += 256) {
        int row = r0 + (c >> 7);
        int xc  = (c & 127) << 2;
        const float* rp = hm + row * WW + xc;
        float4 cur = *(const float4*)rp;
        float4 up  = (row > 0)      ? *(const float4*)(rp - WW) : make_float4(0,0,0,0);
        float4 dn  = (row < HH - 1) ? *(const float4*)(rp + WW) : make_float4(0,0,0,0);
        float lf = (xc > 0)      ? rp[-1] : 0.0f;
        float rt = (xc < WW - 4) ? rp[4]  : 0.0f;
        float V[4] = {cur.x, cur.y, cur.z, cur.w};
        float L[4] = {lf, cur.x, cur.y, cur.z};
        float R[4] = {cur.y, cur.z, cur.w, rt};
        float U[4] = {up.x, up.y, up.z, up.w};
        float D[4] = {dn.x, dn.y, dn.z, dn.w};
#pragma unroll
        for (int k = 0; k < 4; k++) {
            float v = V[k];
            // neighbor<0.1 -> thresholded neighbor is 0 < v
            bool pk = (v >= 0.1f) &&
                      (R[k] < 0.1f || v > R[k]) && (L[k] < 0.1f || v > L[k]) &&
                      (D[k] < 0.1f || v > D[k]) && (U[k] < 0.1f || v > U[k]);
            unsigned long long mask = __ballot(pk);
            if (pk) {
                unsigned bits = __float_as_uint(v);
                unsigned b = (bits - MINB) >> HSHIFT;
                if (b >= NBINS2) b = NBINS2 - 1;
                atomicAdd(&hist[b], 1u);   // spread addresses: cheap
            }
            if (mask) {
                unsigned prefix = (unsigned)__popcll(mask & ((1ull << lane) - 1ull));
                int leader = (int)(__ffsll((unsigned long long)mask) - 1);
                unsigned base = 0;
                if (lane == leader) base = atomicAdd(&s_cnt, (unsigned)__popcll(mask));
                base = (unsigned)__shfl((int)base, leader);
                if (pk) {
                    unsigned pos = base + prefix;
                    if (pos < CAP2)
                        allK[pos] = mkkey(__float_as_uint(v), (unsigned)(row * WW + xc + k));
                }
            }
        }
    }
    __syncthreads();

    {
        unsigned s = 0;
#pragma unroll
        for (int k = 0; k < 4; k++) s += hist[tid * 4 + k];
        chunkSum[tid] = s;
    }
    __syncthreads();
    if (tid == 0) {
        unsigned total = 0;
        for (int k = 0; k < 256; k++) total += chunkSum[k];
        cntWs[map * NS + slab] = total;
        unsigned thr;
        if (total < (unsigned)KTOP) {
            thr = MINB;
        } else {
            unsigned acc = 0; int c = 255;
            for (; c >= 0; c--) {
                if (acc + chunkSum[c] >= (unsigned)KTOP) break;
                acc += chunkSum[c];
            }
            int b = c * 4 + 3;
            unsigned acc2 = acc;
            for (; b >= c * 4; b--) {
                if (acc2 + hist[b] >= (unsigned)KTOP) break;
                acc2 += hist[b];
            }
            thr = MINB + ((unsigned)b << HSHIFT);
        }
        s_thr = thr;
    }
    __syncthreads();
    const unsigned thr = s_thr;
    const unsigned stored = s_cnt;

    if (stored <= (unsigned)CAP2) {
        // LDS-only compaction of candidates >= thr bin (few: plain atomic ok)
        for (unsigned i = tid; i < stored; i += 256) {
            unsigned long long k = allK[i];
            if ((unsigned)(k >> 32) >= thr) {
                unsigned p = atomicAdd(&s_sel, 1u);
                if (p < SELCAP) selK[p] = k;
            }
        }
    } else {
        // fallback (capture overflow — not expected): re-scan global
        for (int p = tid; p < SLAB_ROWS * WW; p += 256) {
            int row = r0 + (p >> 9);
            int x = p & 511;
            const float* rp0 = hm + row * WW;
            float v = rp0[x];
            if (v < 0.1f || __float_as_uint(v) < thr) continue;
            float R_ = (x < WW - 1)  ? rp0[x + 1]  : 0.0f;
            float L_ = (x > 0)       ? rp0[x - 1]  : 0.0f;
            float U_ = (row > 0)     ? rp0[x - WW] : 0.0f;
            float D_ = (row < HH-1)  ? rp0[x + WW] : 0.0f;
            bool pk = (R_ < 0.1f || v > R_) && (L_ < 0.1f || v > L_) &&
                      (D_ < 0.1f || v > D_) && (U_ < 0.1f || v > U_);
            if (pk) {
                unsigned p2 = atomicAdd(&s_sel, 1u);
                if (p2 < SELCAP) selK[p2] = mkkey(__float_as_uint(v), (unsigned)(row * WW + x));
            }
        }
    }
    __syncthreads();
    int m = (int)(s_sel < (unsigned)SELCAP ? s_sel : (unsigned)SELCAP);

    // exact rank among selected (all non-selected keys are strictly smaller)
    for (int i = tid; i < m; i += 256) {
        unsigned long long ki = selK[i];
        int rank = 0;
        for (int j = 0; j < m; j++) rank += (int)(selK[j] > ki);
        if (rank < KTOP) topK[rank] = ki;
    }
    __syncthreads();
    if (tid < KTOP)
        candWs[(size_t)(map * NS + slab) * KTOP + tid] = topK[tid];
}

// Pass 2: per-map merge of 32x64 candidates -> exact top-64, x-sort, NMS.
// Pivot prefilter: pivot = max_s (slab s's 64th key). Any key < pivot has
// >=64 larger keys (the pivot slab's full list), so only survivors >= pivot
// need the n^2 rank; survivor rank == global rank.
__global__ __launch_bounds__(1024) void merge_kernel(
    const float* __restrict__ hm_all,
    const unsigned long long* __restrict__ candWs, const unsigned* __restrict__ cntWs,
    float* __restrict__ coords, float* __restrict__ ss, float* __restrict__ ks)
{
    const int map = blockIdx.x;
    const int tid = threadIdx.x;

    __shared__ unsigned long long cK[NS * KTOP];
    __shared__ unsigned long long selK[SELCAP];
    __shared__ int sx[KTOP], sy[KTOP], svalid[KTOP];
    __shared__ float sv[KTOP];
    __shared__ int ox[KTOP], oyv[KTOP], oval[KTOP];
    __shared__ float osc[KTOP];
    __shared__ unsigned s_total, s_nsel;
    __shared__ unsigned long long s_pivot;

    for (int t = tid; t < NS * KTOP; t += 1024)
        cK[t] = candWs[(size_t)map * NS * KTOP + t];
    if (tid == 0) {
        unsigned t = 0;
        for (int s = 0; s < NS; s++) t += cntWs[map * NS + s];
        s_total = t;
        s_nsel = 0u;
    }
    if (tid < KTOP) svalid[tid] = 0;
    __syncthreads();
    if (tid == 0) {
        unsigned long long pv = 0ull;
        for (int s = 0; s < NS; s++) {
            unsigned long long t = cK[s * KTOP + KTOP - 1];
            if (t > pv) pv = t;
        }
        s_pivot = pv;
    }
    const unsigned total = s_total;
    __syncthreads();
    const unsigned long long pivot = s_pivot;

    for (int t = tid; t < NS * KTOP; t += 1024) {
        unsigned long long k = cK[t];
        if (k != 0ull && k >= pivot) {
            unsigned p = atomicAdd(&s_nsel, 1u);
            if (p < SELCAP) selK[p] = k;
        }
    }
    __syncthreads();

    if (s_nsel <= (unsigned)SELCAP) {
        int m = (int)s_nsel;
        for (int i = tid; i < m; i += 1024) {
            unsigned long long ki = selK[i];
            int rank = 0;
            for (int j = 0; j < m; j++) rank += (int)(selK[j] > ki);
            if (rank < KTOP) {
                unsigned ii = ~(unsigned)ki;
                sx[rank] = (int)(ii & 511u);
                sy[rank] = (int)(ii >> 9);
                sv[rank] = __uint_as_float((unsigned)(ki >> 32));
                svalid[rank] = 1;
            }
        }
    } else {
        // fallback: full rank (rare; correctness-preserving)
        for (int t = tid; t < NS * KTOP; t += 1024) {
            unsigned long long ki = cK[t];
            if (ki != 0ull) {
                int rank = 0;
                for (int j = 0; j < NS * KTOP; j++) rank += (int)(cK[j] > ki);
                if (rank < KTOP) {
                    unsigned ii = ~(unsigned)ki;
                    sx[rank] = (int)(ii & 511u);
                    sy[rank] = (int)(ii >> 9);
                    sv[rank] = __uint_as_float((unsigned)(ki >> 32));
                    svalid[rank] = 1;
                }
            }
        }
    }
    __syncthreads();

    // Filler (only when a map has <64 peaks): smallest-index non-peak pixels.
    if (total < (unsigned)KTOP && tid == 0) {
        const float* hm = hm_all + (size_t)map * NPIX;
        auto tval = [&](int y, int x) -> float {
            if ((unsigned)x >= (unsigned)WW || (unsigned)y >= (unsigned)HH) return 0.0f;
            float v = hm[y * WW + x];
            return v < 0.1f ? 0.0f : v;
        };
        int cnt = (int)total;
        for (int p = 0; p < NPIX && cnt < KTOP; p++) {
            float v = hm[p];
            float tv = v < 0.1f ? 0.0f : v;
            int y = p >> 9, x = p & 511;
            bool pk = (tv > tval(y, x + 1)) && (tv > tval(y, x - 1)) &&
                      (tv > tval(y + 1, x)) && (tv > tval(y - 1, x));
            if (!pk) { sx[cnt] = x; sy[cnt] = y; sv[cnt] = tv; svalid[cnt] = 0; cnt++; }
        }
    }
    __syncthreads();

    // Stable sort by (x asc, rank asc); invalid keyed at W+1
    if (tid < KTOP) {
        int xk = svalid[tid] ? sx[tid] : (WW + 1);
        int fpos = 0;
        for (int t = 0; t < KTOP; t++) {
            int xkt = svalid[t] ? sx[t] : (WW + 1);
            fpos += (int)((xkt < xk) || (xkt == xk && t < tid));
        }
        ox[fpos] = sx[tid]; oyv[fpos] = sy[tid]; osc[fpos] = sv[tid]; oval[fpos] = svalid[tid];
    }
    __syncthreads();

    if (tid < KTOP) {
        int x = ox[tid], y = oyv[tid];
        float sc = osc[tid];
        int valid = oval[tid];
        int keep = valid;
        for (int i = 0; i < KTOP; i++) {
            int ki = __shfl(keep, i);
            int xi = __shfl(x, i);
            int yi = __shfl(y, i);
            if (ki && tid > i) {
                int ddx = x - xi, ddy = y - yi;
                if (ddx * ddx + ddy * ddy < 36) keep = 0;
            }
        }
        size_t base = (size_t)map * KTOP + tid;
        coords[base * 2 + 0] = 2.0f * (float)x;
        coords[base * 2 + 1] = 2.0f * (float)y;
        ss[base] = sc;
        ks[base] = keep ? 1.0f : 0.0f;
    }
}

// Limbs: XCD swizzle + two-phase batch reject. Phase A tests samples
// {0,3,6,9} with 8 independent loads; >=2 fails -> outputs are exactly 0
// (npass>=9 impossible). Otherwise phase B loads the rest; accumulation
// runs in reference order k=0..9. Removes the serial load->branch chain.
__global__ __launch_bounds__(256) void limbs_kernel(
    const float* __restrict__ paf_all,
    const float* __restrict__ coords, const float* __restrict__ ss, const float* __restrict__ ks,
    float* __restrict__ conn, float* __restrict__ cvalid)
{
    const int B = blockIdx.x;
    const int xcd = B & 7;
    const int seq = B >> 3;               // 0..303
    const int bl  = xcd * 19 + (seq >> 4);// b*19 + l
    const int q   = seq & 15;
    const int b = bl / 19, l = bl % 19;
    const int tid = threadIdx.x;

    __shared__ float axs[64], ays[64], sas[64];
    __shared__ float bxs[64], bys[64], sbs[64];
    __shared__ int kas[64], kbs[64];

    const int cA = KPT_A[l], cB = KPT_B[l];
    if (tid < 64) {
        size_t ia = (size_t)(b * 19 + cA) * 64 + tid;
        axs[tid] = coords[ia * 2]     * 0.5f;
        ays[tid] = coords[ia * 2 + 1] * 0.5f;
        sas[tid] = ss[ia];
        kas[tid] = ks[ia] > 0.5f;
    } else if (tid < 128) {
        int t = tid - 64;
        size_t ib = (size_t)(b * 19 + cB) * 64 + t;
        bxs[t] = coords[ib * 2]     * 0.5f;
        bys[t] = coords[ib * 2 + 1] * 0.5f;
        sbs[t] = ss[ib];
        kbs[t] = ks[ib] > 0.5f;
    }
    __syncthreads();

    const float* __restrict__ pafx = paf_all + ((size_t)b * 38 + PAF_X[l]) * NPIX;
    const float* __restrict__ pafy = paf_all + ((size_t)b * 38 + PAF_Y[l]) * NPIX;

    const int pair = q * 256 + tid;
    const int i = pair >> 6, j = pair & 63;

    float score = 0.0f, cval = 0.0f;
    if (kas[i] && kbs[j]) {
        float ax = axs[i], ay = ays[i];
        float bx = bxs[j], by = bys[j];
        float dx = bx - ax, dy = by - ay;
        float norm = sqrtf(__fadd_rn(__fmul_rn(dx, dx), __fmul_rn(dy, dy)));
        float safe = fmaxf(norm, 1e-6f);
        float ux = dx / safe, uy = dy / safe;

        auto offs = [&](float tk) -> int {
            float pxf = __fadd_rn(ax, __fmul_rn(tk, dx));
            float pyf = __fadd_rn(ay, __fmul_rn(tk, dy));
            int px = (int)rintf(pxf); px = px < 0 ? 0 : (px > WW - 1 ? WW - 1 : px);
            int py = (int)rintf(pyf); py = py < 0 ? 0 : (py > HH - 1 ? HH - 1 : py);
            return py * WW + px;
        };
        auto sc_of = [&](float px_, float py_) -> float {
            return __fadd_rn(__fmul_rn(ux, px_), __fmul_rn(uy, py_));
        };

        // Phase A: samples 0, 3, 6, 9 — 8 independent gathers.
        int o0 = offs(0.0f), o3 = offs(3.0f / 9.0f), o6 = offs(6.0f / 9.0f), o9 = offs(1.0f);
        float fx0 = pafx[o0], fy0 = pafy[o0];
        float fx3 = pafx[o3], fy3 = pafy[o3];
        float fx6 = pafx[o6], fy6 = pafy[o6];
        float fx9 = pafx[o9], fy9 = pafy[o9];
        float s0 = sc_of(fx0, fy0), s3 = sc_of(fx3, fy3);
        float s6 = sc_of(fx6, fy6), s9 = sc_of(fx9, fy9);
        int failsA = (int)!(s0 > 0.05f) + (int)!(s3 > 0.05f) +
                     (int)!(s6 > 0.05f) + (int)!(s9 > 0.05f);
        if (failsA < 2) {
            // Phase B: samples 1,2,4,5,7,8 — 12 independent gathers.
            int o1 = offs(1.0f / 9.0f), o2 = offs(2.0f / 9.0f);
            int o4 = offs(4.0f / 9.0f), o5 = offs(5.0f / 9.0f);
            int o7 = offs(7.0f / 9.0f), o8 = offs(8.0f / 9.0f);
            float fx1 = pafx[o1], fy1 = pafy[o1];
            float fx2 = pafx[o2], fy2 = pafy[o2];
            float fx4 = pafx[o4], fy4 = pafy[o4];
            float fx5 = pafx[o5], fy5 = pafy[o5];
            float fx7 = pafx[o7], fy7 = pafy[o7];
            float fx8 = pafx[o8], fy8 = pafy[o8];
            float s1 = sc_of(fx1, fy1), s2 = sc_of(fx2, fy2);
            float s4 = sc_of(fx4, fy4), s5 = sc_of(fx5, fy5);
            float s7 = sc_of(fx7, fy7), s8 = sc_of(fx8, fy8);

            int npass = 0;
            float ssum = 0.0f;
#define ACC(S) if ((S) > 0.05f) { npass++; ssum = __fadd_rn(ssum, (S)); }
            ACC(s0) ACC(s1) ACC(s2) ACC(s3) ACC(s4)
            ACC(s5) ACC(s6) ACC(s7) ACC(s8) ACC(s9)
#undef ACC
            float ratio = (npass > 0) ? (ssum / (float)npass) : 0.0f;
            float mpen = fminf(__fsub_rn(256.0f / safe, 1.0f), 0.0f);
            ratio = __fadd_rn(ratio, mpen);
            bool valid = (ratio > 0.0f) && (npass >= 9) && (norm > 0.0f);
            if (valid) {
                score = __fadd_rn(__fadd_rn(ratio, sas[i]), sbs[j]);
                cval = 1.0f;
            }
        }
    }

    size_t o = ((size_t)bl * 64 + i) * 64 + j;
    conn[o] = score;
    cvalid[o] = cval;
}

extern "C" void kernel_launch(void* const* d_in, const int* in_sizes, int n_in,
                              void* d_out, int out_size, void* d_ws, size_t ws_size,
                              hipStream_t stream) {
    const float* hm  = (const float*)d_in[0];
    const float* paf = (const float*)d_in[1];
    float* out = (float*)d_out;

    // Output layout (flat, return order): coords, ss, ks, conn, cvalid
    float* coords = out;                 // 8*19*64*2 = 19456
    float* ss     = out + 19456;         // 8*19*64   = 9728
    float* ks     = out + 29184;         // 8*19*64   = 9728
    float* conn   = out + 38912;         // 8*19*64*64 = 622592
    float* cvalid = out + 661504;        // 8*19*64*64 = 622592

    // Scratch in d_ws: candWs 152*32*64 u64 (2.49 MB) + cntWs.
    unsigned long long* candWs = (unsigned long long*)d_ws;
    unsigned* cntWs = (unsigned*)((char*)d_ws + (size_t)NMAPS * NS * KTOP * 8);

    dim3 gA(NS, NMAPS);
    peaks_slab_kernel<<<gA, 256, 0, stream>>>(hm, candWs, cntWs);
    merge_kernel<<<NMAPS, 1024, 0, stream>>>(hm, candWs, cntWs, coords, ss, ks);
    limbs_kernel<<<NMAPS * 16, 256, 0, stream>>>(paf, coords, ss, ks, conn, cvalid);
}

// Round 8
// 231.457 us; speedup vs baseline: 1.0096x; 1.0096x over previous
//
#include <hip/hip_runtime.h>
#include <hip/hip_bf16.h>

#define HH 512
#define WW 512
#define NPIX (HH * WW)
#define KTOP 64
#define NBINS2 2048
#define NS 16
#define SLAB_ROWS 32
#define CAP2 4096
#define SELCAP 512
#define NMAPS (8 * 19)

static constexpr unsigned MINB = 0x3DCCCCCDu; // bits of 0.1f

__constant__ int KPT_A[19] = {1,1,2,3,5,6,1,8,9,1,11,12,1,0,14,0,15,2,5};
__constant__ int KPT_B[19] = {2,5,3,4,6,7,8,9,10,11,12,13,0,14,16,15,17,16,17};
__constant__ int PAF_X[19] = {12,20,14,16,22,24,0,2,4,6,8,10,28,30,34,32,36,18,26};
__constant__ int PAF_Y[19] = {13,21,15,17,23,25,1,3,5,7,9,11,29,31,35,33,37,19,27};

// key = (value bits << 32) | ~idx  -> rank by key DESC == (value desc, idx asc)
__device__ __forceinline__ unsigned long long mkkey(unsigned bits, unsigned idx) {
    return ((unsigned long long)bits << 32) | (unsigned long long)(~idx);
}

// Pass 1 (R4 version): per-slab (32 rows) exact top-64 peaks. Single global
// scan: histogram + full candidate capture in LDS; selection is LDS-only.
__global__ __launch_bounds__(256) void peaks_slab_kernel(
    const float* __restrict__ hm_all,
    unsigned long long* __restrict__ candWs, unsigned* __restrict__ cntWs)
{
    const int slab = blockIdx.x;
    const int map  = blockIdx.y;
    const float* __restrict__ hm = hm_all + (size_t)map * NPIX;
    const int r0 = slab * SLAB_ROWS;
    const int tid = threadIdx.x;

    __shared__ unsigned hist[NBINS2];
    __shared__ unsigned long long allK[CAP2];
    __shared__ unsigned long long selK[SELCAP];
    __shared__ unsigned chunkSum[256];
    __shared__ unsigned s_cnt, s_sel, s_thr;
    __shared__ unsigned long long topK[KTOP];

    for (int i = tid; i < NBINS2; i += 256) hist[i] = 0u;
    if (tid == 0) { s_cnt = 0u; s_sel = 0u; }
    if (tid < KTOP) topK[tid] = 0ull;
    __syncthreads();

    // scan: float4-vectorized, coalesced. Histogram + capture every peak key.
    for (int c = tid; c < SLAB_ROWS * 128; c += 256) {
        int row = r0 + (c >> 7);
        int xc  = (c & 127) << 2;
        const float* rp = hm + row * WW + xc;
        float4 cur = *(const float4*)rp;
        float4 up  = (row > 0)      ? *(const float4*)(rp - WW) : make_float4(0,0,0,0);
        float4 dn  = (row < HH - 1) ? *(const float4*)(rp + WW) : make_float4(0,0,0,0);
        float lf = (xc > 0)      ? rp[-1] : 0.0f;
        float rt = (xc < WW - 4) ? rp[4]  : 0.0f;
        float V[4] = {cur.x, cur.y, cur.z, cur.w};
        float L[4] = {lf, cur.x, cur.y, cur.z};
        float R[4] = {cur.y, cur.z, cur.w, rt};
        float U[4] = {up.x, up.y, up.z, up.w};
        float D[4] = {dn.x, dn.y, dn.z, dn.w};
#pragma unroll
        for (int k = 0; k < 4; k++) {
            float v = V[k];
            if (v < 0.1f) continue;
            // neighbor<0.1 -> thresholded neighbor is 0 < v
            bool pk = (R[k] < 0.1f || v > R[k]) && (L[k] < 0.1f || v > L[k]) &&
                      (D[k] < 0.1f || v > D[k]) && (U[k] < 0.1f || v > U[k]);
            if (pk) {
                unsigned bits = __float_as_uint(v);
                unsigned b = (bits - MINB) >> 14;
                if (b >= NBINS2) b = NBINS2 - 1;
                atomicAdd(&hist[b], 1u);
                unsigned pos = atomicAdd(&s_cnt, 1u);
                if (pos < CAP2) allK[pos] = mkkey(bits, (unsigned)(row * WW + xc + k));
            }
        }
    }
    __syncthreads();

    {
        unsigned s = 0;
#pragma unroll
        for (int k = 0; k < 8; k++) s += hist[tid * 8 + k];
        chunkSum[tid] = s;
    }
    __syncthreads();
    if (tid == 0) {
        unsigned total = 0;
        for (int k = 0; k < 256; k++) total += chunkSum[k];
        cntWs[map * NS + slab] = total;
        unsigned thr;
        if (total < (unsigned)KTOP) {
            thr = MINB;
        } else {
            unsigned acc = 0; int c = 255;
            for (; c >= 0; c--) {
                if (acc + chunkSum[c] >= (unsigned)KTOP) break;
                acc += chunkSum[c];
            }
            int b = c * 8 + 7;
            unsigned acc2 = acc;
            for (; b >= c * 8; b--) {
                if (acc2 + hist[b] >= (unsigned)KTOP) break;
                acc2 += hist[b];
            }
            thr = MINB + ((unsigned)b << 14);
        }
        s_thr = thr;
    }
    __syncthreads();
    const unsigned thr = s_thr;
    const unsigned stored = s_cnt;

    if (stored <= (unsigned)CAP2) {
        // LDS-only compaction of candidates >= thr bin
        for (unsigned i = tid; i < stored; i += 256) {
            unsigned long long k = allK[i];
            if ((unsigned)(k >> 32) >= thr) {
                unsigned p = atomicAdd(&s_sel, 1u);
                if (p < SELCAP) selK[p] = k;
            }
        }
    } else {
        // fallback (capture overflow — not expected for this data): re-scan global
        for (int p = tid; p < SLAB_ROWS * WW; p += 256) {
            int row = r0 + (p >> 9);
            int x = p & 511;
            const float* rp0 = hm + row * WW;
            float v = rp0[x];
            if (v < 0.1f || __float_as_uint(v) < thr) continue;
            float R_ = (x < WW - 1)  ? rp0[x + 1]  : 0.0f;
            float L_ = (x > 0)       ? rp0[x - 1]  : 0.0f;
            float U_ = (row > 0)     ? rp0[x - WW] : 0.0f;
            float D_ = (row < HH-1)  ? rp0[x + WW] : 0.0f;
            bool pk = (R_ < 0.1f || v > R_) && (L_ < 0.1f || v > L_) &&
                      (D_ < 0.1f || v > D_) && (U_ < 0.1f || v > U_);
            if (pk) {
                unsigned p2 = atomicAdd(&s_sel, 1u);
                if (p2 < SELCAP) selK[p2] = mkkey(__float_as_uint(v), (unsigned)(row * WW + x));
            }
        }
    }
    __syncthreads();
    int m = (int)(s_sel < (unsigned)SELCAP ? s_sel : (unsigned)SELCAP);

    // exact rank among selected (all non-selected keys are strictly smaller)
    for (int i = tid; i < m; i += 256) {
        unsigned long long ki = selK[i];
        int rank = 0;
        for (int j = 0; j < m; j++) rank += (int)(selK[j] > ki);
        if (rank < KTOP) topK[rank] = ki;
    }
    __syncthreads();
    if (tid < KTOP)
        candWs[(size_t)(map * NS + slab) * KTOP + tid] = topK[tid];
}

// Pass 2 (R4 version): per-map merge of 16x64 candidates -> exact top-64,
// x-sort, NMS, write.
__global__ __launch_bounds__(1024) void merge_kernel(
    const float* __restrict__ hm_all,
    const unsigned long long* __restrict__ candWs, const unsigned* __restrict__ cntWs,
    float* __restrict__ coords, float* __restrict__ ss, float* __restrict__ ks)
{
    const int map = blockIdx.x;
    const int tid = threadIdx.x;

    __shared__ unsigned long long cK[NS * KTOP];
    __shared__ int sx[KTOP], sy[KTOP], svalid[KTOP];
    __shared__ float sv[KTOP];
    __shared__ int ox[KTOP], oyv[KTOP], oval[KTOP];
    __shared__ float osc[KTOP];
    __shared__ unsigned s_total;

    cK[tid] = candWs[(size_t)map * NS * KTOP + tid];
    if (tid == 0) {
        unsigned t = 0;
        for (int s = 0; s < NS; s++) t += cntWs[map * NS + s];
        s_total = t;
    }
    if (tid < KTOP) svalid[tid] = 0;
    __syncthreads();
    const unsigned total = s_total;

    {
        unsigned long long ki = cK[tid];
        if (ki != 0ull) {
            int rank = 0;
            for (int j = 0; j < NS * KTOP; j++) rank += (int)(cK[j] > ki);
            if (rank < KTOP) {
                unsigned ii = ~(unsigned)ki;
                sx[rank] = (int)(ii & 511u);
                sy[rank] = (int)(ii >> 9);
                sv[rank] = __uint_as_float((unsigned)(ki >> 32));
                svalid[rank] = 1;
            }
        }
    }
    __syncthreads();

    // Filler (only when a map has <64 peaks): smallest-index non-peak pixels.
    if (total < (unsigned)KTOP && tid == 0) {
        const float* hm = hm_all + (size_t)map * NPIX;
        auto tval = [&](int y, int x) -> float {
            if ((unsigned)x >= (unsigned)WW || (unsigned)y >= (unsigned)HH) return 0.0f;
            float v = hm[y * WW + x];
            return v < 0.1f ? 0.0f : v;
        };
        int cnt = (int)total;
        for (int p = 0; p < NPIX && cnt < KTOP; p++) {
            float v = hm[p];
            float tv = v < 0.1f ? 0.0f : v;
            int y = p >> 9, x = p & 511;
            bool pk = (tv > tval(y, x + 1)) && (tv > tval(y, x - 1)) &&
                      (tv > tval(y + 1, x)) && (tv > tval(y - 1, x));
            if (!pk) { sx[cnt] = x; sy[cnt] = y; sv[cnt] = tv; svalid[cnt] = 0; cnt++; }
        }
    }
    __syncthreads();

    // Stable sort by (x asc, rank asc); invalid keyed at W+1
    if (tid < KTOP) {
        int xk = svalid[tid] ? sx[tid] : (WW + 1);
        int fpos = 0;
        for (int t = 0; t < KTOP; t++) {
            int xkt = svalid[t] ? sx[t] : (WW + 1);
            fpos += (int)((xkt < xk) || (xkt == xk && t < tid));
        }
        ox[fpos] = sx[tid]; oyv[fpos] = sy[tid]; osc[fpos] = sv[tid]; oval[fpos] = svalid[tid];
    }
    __syncthreads();

    if (tid < KTOP) {
        int x = ox[tid], y = oyv[tid];
        float sc = osc[tid];
        int valid = oval[tid];
        int keep = valid;
        for (int i = 0; i < KTOP; i++) {
            int ki = __shfl(keep, i);
            int xi = __shfl(x, i);
            int yi = __shfl(y, i);
            if (ki && tid > i) {
                int ddx = x - xi, ddy = y - yi;
                if (ddx * ddx + ddy * ddy < 36) keep = 0;
            }
        }
        size_t base = (size_t)map * KTOP + tid;
        coords[base * 2 + 0] = 2.0f * (float)x;
        coords[base * 2 + 1] = 2.0f * (float)y;
        ss[base] = sc;
        ks[base] = keep ? 1.0f : 0.0f;
    }
}

// Limbs v3: persistent phase-sequenced blocks. 512 blocks x 256 threads
// (2 blocks/CU, 8 waves/CU). Block B: XCD b = B&7 (== batch), k = B>>3;
// rep = k>>4 walks limbs {5*rep .. 5*rep+4} SEQUENTIALLY (rep3: 4 limbs),
// q = k&15 selects the 256-pair chunk. At most 4 limbs (8 MB) live per XCD
// at a time -> gathers are mostly L2-hit, and each PAF line is HBM-fetched
// once by one XCD. All 20 gathers per pair issue as independent loads (one
// wait, no serial chain); accumulation in exact reference order.
__global__ __launch_bounds__(256) void limbs_kernel(
    const float* __restrict__ paf_all,
    const float* __restrict__ coords, const float* __restrict__ ss, const float* __restrict__ ks,
    float* __restrict__ conn, float* __restrict__ cvalid)
{
    const int B = blockIdx.x;
    const int b   = B & 7;               // XCD == batch
    const int k   = B >> 3;              // 0..63 within XCD
    const int rep = k >> 4;              // 0..3
    const int q   = k & 15;              // pair chunk
    const int tid = threadIdx.x;

    const int lbase = rep * 5;
    const int lcnt  = (rep == 3) ? 4 : 5;

    __shared__ float axs[64], ays[64], sas[64];
    __shared__ float bxs[64], bys[64], sbs[64];
    __shared__ int kas[64], kbs[64];

    for (int step = 0; step < lcnt; ++step) {
        const int l  = lbase + step;
        const int bl = b * 19 + l;
        const int cA = KPT_A[l], cB = KPT_B[l];

        __syncthreads();                 // protect LDS reuse across steps
        if (tid < 64) {
            size_t ia = (size_t)(b * 19 + cA) * 64 + tid;
            axs[tid] = coords[ia * 2]     * 0.5f;
            ays[tid] = coords[ia * 2 + 1] * 0.5f;
            sas[tid] = ss[ia];
            kas[tid] = ks[ia] > 0.5f;
        } else if (tid < 128) {
            int t = tid - 64;
            size_t ib = (size_t)(b * 19 + cB) * 64 + t;
            bxs[t] = coords[ib * 2]     * 0.5f;
            bys[t] = coords[ib * 2 + 1] * 0.5f;
            sbs[t] = ss[ib];
            kbs[t] = ks[ib] > 0.5f;
        }
        __syncthreads();

        const float* __restrict__ pafx = paf_all + ((size_t)b * 38 + PAF_X[l]) * NPIX;
        const float* __restrict__ pafy = paf_all + ((size_t)b * 38 + PAF_Y[l]) * NPIX;

        const int pair = q * 256 + tid;
        const int i = pair >> 6, j = pair & 63;   // i wave-uniform

        float score = 0.0f, cval = 0.0f;
        if (kas[i] && kbs[j]) {
            float ax = axs[i], ay = ays[i];
            float bx = bxs[j], by = bys[j];
            float dx = bx - ax, dy = by - ay;
            float norm = sqrtf(__fadd_rn(__fmul_rn(dx, dx), __fmul_rn(dy, dy)));
            float safe = fmaxf(norm, 1e-6f);
            float ux = dx / safe, uy = dy / safe;

            // 20 independent gathers (full unroll -> static indices -> regs).
            float pfx[10], pfy[10];
#pragma unroll
            for (int t = 0; t < 10; t++) {
                const float tk = (float)t / 9.0f;   // constant-folded; t=9 -> 1.0f
                float pxf = __fadd_rn(ax, __fmul_rn(tk, dx));
                float pyf = __fadd_rn(ay, __fmul_rn(tk, dy));
                int px = (int)rintf(pxf); px = px < 0 ? 0 : (px > WW - 1 ? WW - 1 : px);
                int py = (int)rintf(pyf); py = py < 0 ? 0 : (py > HH - 1 ? HH - 1 : py);
                int off = py * WW + px;
                pfx[t] = pafx[off];
                pfy[t] = pafy[off];
            }
            int npass = 0;
            float ssum = 0.0f;
#pragma unroll
            for (int t = 0; t < 10; t++) {
                float sc = __fadd_rn(__fmul_rn(ux, pfx[t]), __fmul_rn(uy, pfy[t]));
                if (sc > 0.05f) { npass++; ssum = __fadd_rn(ssum, sc); }
            }
            float ratio = (npass > 0) ? (ssum / (float)npass) : 0.0f;
            float mpen = fminf(__fsub_rn(256.0f / safe, 1.0f), 0.0f);
            ratio = __fadd_rn(ratio, mpen);
            bool valid = (ratio > 0.0f) && (npass >= 9) && (norm > 0.0f);
            if (valid) {
                score = __fadd_rn(__fadd_rn(ratio, sas[i]), sbs[j]);
                cval = 1.0f;
            }
        }

        size_t o = ((size_t)bl * 64 + i) * 64 + j;
        conn[o] = score;
        cvalid[o] = cval;
    }
}

extern "C" void kernel_launch(void* const* d_in, const int* in_sizes, int n_in,
                              void* d_out, int out_size, void* d_ws, size_t ws_size,
                              hipStream_t stream) {
    const float* hm  = (const float*)d_in[0];
    const float* paf = (const float*)d_in[1];
    float* out = (float*)d_out;

    // Output layout (flat, return order): coords, ss, ks, conn, cvalid
    float* coords = out;                 // 8*19*64*2 = 19456
    float* ss     = out + 19456;         // 8*19*64   = 9728
    float* ks     = out + 29184;         // 8*19*64   = 9728
    float* conn   = out + 38912;         // 8*19*64*64 = 622592
    float* cvalid = out + 661504;        // 8*19*64*64 = 622592

    // Scratch in d_ws: candWs 152*16*64 u64 + cntWs.
    unsigned long long* candWs = (unsigned long long*)d_ws;
    unsigned* cntWs = (unsigned*)((char*)d_ws + (size_t)NMAPS * NS * KTOP * 8);

    dim3 gA(NS, NMAPS);
    peaks_slab_kernel<<<gA, 256, 0, stream>>>(hm, candWs, cntWs);
    merge_kernel<<<NMAPS, 1024, 0, stream>>>(hm, candWs, cntWs, coords, ss, ks);
    limbs_kernel<<<512, 256, 0, stream>>>(paf, coords, ss, ks, conn, cvalid);
}

// Round 9
// 142.889 us; speedup vs baseline: 1.6354x; 1.6198x over previous
//
#include <hip/hip_runtime.h>
#include <hip/hip_bf16.h>

#define HH 512
#define WW 512
#define NPIX (HH * WW)
#define KTOP 64
#define NS 16
#define SLAB_ROWS 32
#define SEGCAP 512
#define SELCAP 512
#define NHIST 256
#define NMAPS (8 * 19)

static constexpr unsigned MINB   = 0x3DCCCCCDu; // bits of 0.1f
static constexpr unsigned T0BITS = 0x3F666666u; // bits of 0.9f (capture pre-threshold)

__constant__ int KPT_A[19] = {1,1,2,3,5,6,1,8,9,1,11,12,1,0,14,0,15,2,5};
__constant__ int KPT_B[19] = {2,5,3,4,6,7,8,9,10,11,12,13,0,14,16,15,17,16,17};
__constant__ int PAF_X[19] = {12,20,14,16,22,24,0,2,4,6,8,10,28,30,34,32,36,18,26};
__constant__ int PAF_Y[19] = {13,21,15,17,23,25,1,3,5,7,9,11,29,31,35,33,37,19,27};

// key = (value bits << 32) | ~idx  -> rank by key DESC == (value desc, idx asc)
__device__ __forceinline__ unsigned long long mkkey(unsigned bits, unsigned idx) {
    return ((unsigned long long)bits << 32) | (unsigned long long)(~idx);
}

// Pass 1: per-slab (32 rows) exact top-64 peaks, atomic-free capture.
// Only peaks with v >= 0.9 are captured (ballot-compacted into per-wave LDS
// segments, counts kept in registers). Exact because: if captured >= 64, all
// uncaptured peaks (< 0.9) are strictly below every captured key, so the
// slab top-64 is inside the captured set. Otherwise (never for this data) a
// serial exact fallback runs. True peak totals are register-counted.
__global__ __launch_bounds__(256) void peaks_slab_kernel(
    const float* __restrict__ hm_all,
    unsigned long long* __restrict__ candWs, unsigned* __restrict__ cntWs)
{
    const int slab = blockIdx.x;
    const int map  = blockIdx.y;
    const float* __restrict__ hm = hm_all + (size_t)map * NPIX;
    const int r0 = slab * SLAB_ROWS;
    const int tid = threadIdx.x;
    const int wid = tid >> 6, lane = tid & 63;

    __shared__ unsigned long long allK[4 * SEGCAP];
    __shared__ unsigned long long selK[SELCAP];
    __shared__ unsigned long long topK[KTOP];
    __shared__ unsigned hist[NHIST];
    __shared__ unsigned segCnt[4], pcnt4[4];
    __shared__ unsigned s_sel, s_thr, s_fb, s_msel, s_total, s_captured;

    for (int i = tid; i < NHIST; i += 256) hist[i] = 0u;
    if (tid == 0) { s_sel = 0u; s_fb = 0u; }
    if (tid < KTOP) topK[tid] = 0ull;
    __syncthreads();

    const unsigned long long laneBelow = (1ull << lane) - 1ull;
    unsigned ccnt = 0;   // captured count (wave-uniform)
    unsigned pcnt = 0;   // true peak count (wave-uniform)
    const unsigned wbase = (unsigned)wid * SEGCAP;

    // single coalesced scan: float4-vectorized peak test, ballot compaction
    for (int c = tid; c < SLAB_ROWS * 128; c += 256) {
        int row = r0 + (c >> 7);
        int xc  = (c & 127) << 2;
        const float* rp = hm + row * WW + xc;
        float4 cur = *(const float4*)rp;
        float4 up  = (row > 0)      ? *(const float4*)(rp - WW) : make_float4(0,0,0,0);
        float4 dn  = (row < HH - 1) ? *(const float4*)(rp + WW) : make_float4(0,0,0,0);
        float lf = (xc > 0)      ? rp[-1] : 0.0f;
        float rt = (xc < WW - 4) ? rp[4]  : 0.0f;
        float V[4] = {cur.x, cur.y, cur.z, cur.w};
        float L[4] = {lf, cur.x, cur.y, cur.z};
        float R[4] = {cur.y, cur.z, cur.w, rt};
        float U[4] = {up.x, up.y, up.z, up.w};
        float D[4] = {dn.x, dn.y, dn.z, dn.w};
#pragma unroll
        for (int k = 0; k < 4; k++) {
            float v = V[k];
            // neighbor<0.1 -> thresholded neighbor is 0 < v (since v>=0.1)
            bool pk = (v >= 0.1f) &&
                      (R[k] < 0.1f || v > R[k]) && (L[k] < 0.1f || v > L[k]) &&
                      (D[k] < 0.1f || v > D[k]) && (U[k] < 0.1f || v > U[k]);
            unsigned bits = __float_as_uint(v);
            bool cap = pk && (bits >= T0BITS);
            unsigned long long pmask = __ballot(pk);
            unsigned long long cmask = __ballot(cap);
            if (cap) {
                unsigned pos = ccnt + (unsigned)__popcll(cmask & laneBelow);
                if (pos < SEGCAP)
                    allK[wbase + pos] = mkkey(bits, (unsigned)(row * WW + xc + k));
                else
                    s_fb = 1u;  // segment overflow (10+ sigma; race-benign)
            }
            ccnt += (unsigned)__popcll(cmask);
            pcnt += (unsigned)__popcll(pmask);
        }
    }
    if (lane == 0) {
        segCnt[wid] = ccnt < SEGCAP ? ccnt : SEGCAP;
        pcnt4[wid] = pcnt;
    }
    __syncthreads();

    if (tid == 0) {
        unsigned total = pcnt4[0] + pcnt4[1] + pcnt4[2] + pcnt4[3];
        unsigned captured = segCnt[0] + segCnt[1] + segCnt[2] + segCnt[3];
        s_total = total;
        s_captured = captured;
        // must fall back if some peaks are uncaptured AND captured < 64
        if (captured < (unsigned)KTOP && captured < total) s_fb = 1u;
        cntWs[map * NS + slab] = total;
    }
    __syncthreads();

    if (s_fb == 0u) {
        const unsigned captured = s_captured;
        // 256-bin histogram over captured value bits (spread atomics, ~1300)
        for (int w = 0; w < 4; w++) {
            unsigned n = segCnt[w];
            for (unsigned i = tid; i < n; i += 256) {
                unsigned bits = (unsigned)(allK[w * SEGCAP + i] >> 32);
                unsigned b = (bits - T0BITS) >> 13;
                if (b >= NHIST) b = NHIST - 1;
                atomicAdd(&hist[b], 1u);
            }
        }
        __syncthreads();
        if (tid == 0) {
            unsigned thrBits, msel;
            if (captured < (unsigned)KTOP) {
                thrBits = T0BITS; msel = captured;   // captured==total here
            } else {
                unsigned acc = 0; int b = NHIST - 1;
                for (; b >= 0; b--) {
                    acc += hist[b];
                    if (acc >= (unsigned)KTOP) break;
                }
                thrBits = T0BITS + ((unsigned)b << 13);
                msel = acc;
            }
            s_thr = thrBits;
            s_msel = msel;
            if (msel > (unsigned)SELCAP) s_fb = 1u;  // pathological tie cluster
        }
        __syncthreads();
    }

    if (s_fb == 0u) {
        const unsigned thrBits = s_thr;
        // select survivors (>= thr) — ~64-90 entries, tiny atomic count
        for (int w = 0; w < 4; w++) {
            unsigned n = segCnt[w];
            for (unsigned i = tid; i < n; i += 256) {
                unsigned long long k = allK[w * SEGCAP + i];
                if ((unsigned)(k >> 32) >= thrBits) {
                    unsigned p = atomicAdd(&s_sel, 1u);
                    selK[p] = k;
                }
            }
        }
        __syncthreads();
        int m = (int)s_sel;
        // exact rank among survivors (every non-survivor is strictly smaller)
        for (int i = tid; i < m; i += 256) {
            unsigned long long ki = selK[i];
            int rank = 0;
            for (int j = 0; j < m; j++) rank += (int)(selK[j] > ki);
            if (rank < KTOP) topK[rank] = ki;
        }
        __syncthreads();
    } else {
        // exact serial fallback (unreachable for benchmark data)
        if (tid == 0) {
            for (int t = 0; t < KTOP; t++) topK[t] = 0ull;
            unsigned total = 0;
            for (int p = 0; p < SLAB_ROWS * WW; p++) {
                int row = r0 + (p >> 9), x = p & 511;
                float v = hm[row * WW + x];
                if (v < 0.1f) continue;
                float R_ = (x < WW - 1)  ? hm[row * WW + x + 1] : 0.0f;
                float L_ = (x > 0)       ? hm[row * WW + x - 1] : 0.0f;
                float U_ = (row > 0)     ? hm[(row - 1) * WW + x] : 0.0f;
                float D_ = (row < HH-1)  ? hm[(row + 1) * WW + x] : 0.0f;
                bool pk = (R_ < 0.1f || v > R_) && (L_ < 0.1f || v > L_) &&
                          (D_ < 0.1f || v > D_) && (U_ < 0.1f || v > U_);
                if (pk) {
                    total++;
                    unsigned long long key = mkkey(__float_as_uint(v),
                                                   (unsigned)(row * WW + x));
                    if (key > topK[KTOP - 1]) {
                        int t = KTOP - 1;
                        while (t > 0 && topK[t - 1] < key) { topK[t] = topK[t - 1]; t--; }
                        topK[t] = key;
                    }
                }
            }
            cntWs[map * NS + slab] = total;
        }
        __syncthreads();
    }

    if (tid < KTOP)
        candWs[(size_t)(map * NS + slab) * KTOP + tid] = topK[tid];
}

// Pass 2 (R4 version): per-map merge of 16x64 candidates -> exact top-64,
// x-sort, NMS, write.
__global__ __launch_bounds__(1024) void merge_kernel(
    const float* __restrict__ hm_all,
    const unsigned long long* __restrict__ candWs, const unsigned* __restrict__ cntWs,
    float* __restrict__ coords, float* __restrict__ ss, float* __restrict__ ks)
{
    const int map = blockIdx.x;
    const int tid = threadIdx.x;

    __shared__ unsigned long long cK[NS * KTOP];
    __shared__ int sx[KTOP], sy[KTOP], svalid[KTOP];
    __shared__ float sv[KTOP];
    __shared__ int ox[KTOP], oyv[KTOP], oval[KTOP];
    __shared__ float osc[KTOP];
    __shared__ unsigned s_total;

    cK[tid] = candWs[(size_t)map * NS * KTOP + tid];
    if (tid == 0) {
        unsigned t = 0;
        for (int s = 0; s < NS; s++) t += cntWs[map * NS + s];
        s_total = t;
    }
    if (tid < KTOP) svalid[tid] = 0;
    __syncthreads();
    const unsigned total = s_total;

    {
        unsigned long long ki = cK[tid];
        if (ki != 0ull) {
            int rank = 0;
            for (int j = 0; j < NS * KTOP; j++) rank += (int)(cK[j] > ki);
            if (rank < KTOP) {
                unsigned ii = ~(unsigned)ki;
                sx[rank] = (int)(ii & 511u);
                sy[rank] = (int)(ii >> 9);
                sv[rank] = __uint_as_float((unsigned)(ki >> 32));
                svalid[rank] = 1;
            }
        }
    }
    __syncthreads();

    // Filler (only when a map has <64 peaks): smallest-index non-peak pixels.
    if (total < (unsigned)KTOP && tid == 0) {
        const float* hm = hm_all + (size_t)map * NPIX;
        auto tval = [&](int y, int x) -> float {
            if ((unsigned)x >= (unsigned)WW || (unsigned)y >= (unsigned)HH) return 0.0f;
            float v = hm[y * WW + x];
            return v < 0.1f ? 0.0f : v;
        };
        int cnt = (int)total;
        for (int p = 0; p < NPIX && cnt < KTOP; p++) {
            float v = hm[p];
            float tv = v < 0.1f ? 0.0f : v;
            int y = p >> 9, x = p & 511;
            bool pk = (tv > tval(y, x + 1)) && (tv > tval(y, x - 1)) &&
                      (tv > tval(y + 1, x)) && (tv > tval(y - 1, x));
            if (!pk) { sx[cnt] = x; sy[cnt] = y; sv[cnt] = tv; svalid[cnt] = 0; cnt++; }
        }
    }
    __syncthreads();

    // Stable sort by (x asc, rank asc); invalid keyed at W+1
    if (tid < KTOP) {
        int xk = svalid[tid] ? sx[tid] : (WW + 1);
        int fpos = 0;
        for (int t = 0; t < KTOP; t++) {
            int xkt = svalid[t] ? sx[t] : (WW + 1);
            fpos += (int)((xkt < xk) || (xkt == xk && t < tid));
        }
        ox[fpos] = sx[tid]; oyv[fpos] = sy[tid]; osc[fpos] = sv[tid]; oval[fpos] = svalid[tid];
    }
    __syncthreads();

    if (tid < KTOP) {
        int x = ox[tid], y = oyv[tid];
        float sc = osc[tid];
        int valid = oval[tid];
        int keep = valid;
        for (int i = 0; i < KTOP; i++) {
            int ki = __shfl(keep, i);
            int xi = __shfl(x, i);
            int yi = __shfl(y, i);
            if (ki && tid > i) {
                int ddx = x - xi, ddy = y - yi;
                if (ddx * ddx + ddy * ddy < 36) keep = 0;
            }
        }
        size_t base = (size_t)map * KTOP + tid;
        coords[base * 2 + 0] = 2.0f * (float)x;
        coords[base * 2 + 1] = 2.0f * (float)y;
        ss[base] = sc;
        ks[base] = keep ? 1.0f : 0.0f;
    }
}

// Limbs (R4 version: XCD swizzle + early-exit; high occupancy).
__global__ __launch_bounds__(256) void limbs_kernel(
    const float* __restrict__ paf_all,
    const float* __restrict__ coords, const float* __restrict__ ss, const float* __restrict__ ks,
    float* __restrict__ conn, float* __restrict__ cvalid)
{
    const int B = blockIdx.x;
    const int xcd = B & 7;
    const int seq = B >> 3;               // 0..303
    const int bl  = xcd * 19 + (seq >> 4);// b*19 + l
    const int q   = seq & 15;
    const int b = bl / 19, l = bl % 19;
    const int tid = threadIdx.x;

    __shared__ float axs[64], ays[64], sas[64];
    __shared__ float bxs[64], bys[64], sbs[64];
    __shared__ int kas[64], kbs[64];

    const int cA = KPT_A[l], cB = KPT_B[l];
    if (tid < 64) {
        size_t ia = (size_t)(b * 19 + cA) * 64 + tid;
        axs[tid] = coords[ia * 2]     * 0.5f;
        ays[tid] = coords[ia * 2 + 1] * 0.5f;
        sas[tid] = ss[ia];
        kas[tid] = ks[ia] > 0.5f;
    } else if (tid < 128) {
        int t = tid - 64;
        size_t ib = (size_t)(b * 19 + cB) * 64 + t;
        bxs[t] = coords[ib * 2]     * 0.5f;
        bys[t] = coords[ib * 2 + 1] * 0.5f;
        sbs[t] = ss[ib];
        kbs[t] = ks[ib] > 0.5f;
    }
    __syncthreads();

    const float* __restrict__ pafx = paf_all + ((size_t)b * 38 + PAF_X[l]) * NPIX;
    const float* __restrict__ pafy = paf_all + ((size_t)b * 38 + PAF_Y[l]) * NPIX;

    const int pair = q * 256 + tid;
    const int i = pair >> 6, j = pair & 63;

    float score = 0.0f, cval = 0.0f;
    if (kas[i] && kbs[j]) {
        float ax = axs[i], ay = ays[i];
        float bx = bxs[j], by = bys[j];
        float dx = bx - ax, dy = by - ay;
        float norm = sqrtf(__fadd_rn(__fmul_rn(dx, dx), __fmul_rn(dy, dy)));
        float safe = fmaxf(norm, 1e-6f);
        float ux = dx / safe, uy = dy / safe;

        int npass = 0, fails = 0;
        float ssum = 0.0f;
        // Early exit after 2nd failing sample: npass>=9 then impossible, and
        // every output is exactly 0 in that case — bit-identical shortcut.
#define SAMPLE(TK)                                                              \
        {                                                                       \
            float pxf = __fadd_rn(ax, __fmul_rn((TK), dx));                     \
            float pyf = __fadd_rn(ay, __fmul_rn((TK), dy));                     \
            int px = (int)rintf(pxf); px = px < 0 ? 0 : (px > WW - 1 ? WW - 1 : px); \
            int py = (int)rintf(pyf); py = py < 0 ? 0 : (py > HH - 1 ? HH - 1 : py); \
            int off = py * WW + px;                                             \
            float sc = __fadd_rn(__fmul_rn(ux, pafx[off]), __fmul_rn(uy, pafy[off])); \
            if (sc > 0.05f) { npass++; ssum = __fadd_rn(ssum, sc); }            \
            else if (++fails == 2) goto reject;                                 \
        }
        SAMPLE(0.0f)
        SAMPLE(1.0f / 9.0f)
        SAMPLE(2.0f / 9.0f)
        SAMPLE(3.0f / 9.0f)
        SAMPLE(4.0f / 9.0f)
        SAMPLE(5.0f / 9.0f)
        SAMPLE(6.0f / 9.0f)
        SAMPLE(7.0f / 9.0f)
        SAMPLE(8.0f / 9.0f)
        SAMPLE(1.0f)
#undef SAMPLE
        {
            float ratio = (npass > 0) ? (ssum / (float)npass) : 0.0f;
            float mpen = fminf(__fsub_rn(256.0f / safe, 1.0f), 0.0f);
            ratio = __fadd_rn(ratio, mpen);
            bool valid = (ratio > 0.0f) && (npass >= 9) && (norm > 0.0f);
            if (valid) {
                score = __fadd_rn(__fadd_rn(ratio, sas[i]), sbs[j]);
                cval = 1.0f;
            }
        }
reject: ;
    }

    size_t o = ((size_t)bl * 64 + i) * 64 + j;
    conn[o] = score;
    cvalid[o] = cval;
}

extern "C" void kernel_launch(void* const* d_in, const int* in_sizes, int n_in,
                              void* d_out, int out_size, void* d_ws, size_t ws_size,
                              hipStream_t stream) {
    const float* hm  = (const float*)d_in[0];
    const float* paf = (const float*)d_in[1];
    float* out = (float*)d_out;

    // Output layout (flat, return order): coords, ss, ks, conn, cvalid
    float* coords = out;                 // 8*19*64*2 = 19456
    float* ss     = out + 19456;         // 8*19*64   = 9728
    float* ks     = out + 29184;         // 8*19*64   = 9728
    float* conn   = out + 38912;         // 8*19*64*64 = 622592
    float* cvalid = out + 661504;        // 8*19*64*64 = 622592

    // Scratch in d_ws: candWs 152*16*64 u64 + cntWs.
    unsigned long long* candWs = (unsigned long long*)d_ws;
    unsigned* cntWs = (unsigned*)((char*)d_ws + (size_t)NMAPS * NS * KTOP * 8);

    dim3 gA(NS, NMAPS);
    peaks_slab_kernel<<<gA, 256, 0, stream>>>(hm, candWs, cntWs);
    merge_kernel<<<NMAPS, 1024, 0, stream>>>(hm, candWs, cntWs, coords, ss, ks);
    limbs_kernel<<<NMAPS * 16, 256, 0, stream>>>(paf, coords, ss, ks, conn, cvalid);
}

// Round 10
// 138.028 us; speedup vs baseline: 1.6929x; 1.0352x over previous
//
#include <hip/hip_runtime.h>
#include <hip/hip_bf16.h>

#define HH 512
#define WW 512
#define NPIX (HH * WW)
#define KTOP 64
#define NS 16
#define SLAB_ROWS 32
#define SEGCAP 512
#define SELCAP 512
#define NHIST 256
#define NMAPS (8 * 19)

static constexpr unsigned MINB   = 0x3DCCCCCDu; // bits of 0.1f
static constexpr unsigned T0BITS = 0x3F666666u; // bits of 0.9f (capture pre-threshold)

__constant__ int KPT_A[19] = {1,1,2,3,5,6,1,8,9,1,11,12,1,0,14,0,15,2,5};
__constant__ int KPT_B[19] = {2,5,3,4,6,7,8,9,10,11,12,13,0,14,16,15,17,16,17};
__constant__ int PAF_X[19] = {12,20,14,16,22,24,0,2,4,6,8,10,28,30,34,32,36,18,26};
__constant__ int PAF_Y[19] = {13,21,15,17,23,25,1,3,5,7,9,11,29,31,35,33,37,19,27};

// key = (value bits << 32) | ~idx  -> rank by key DESC == (value desc, idx asc)
__device__ __forceinline__ unsigned long long mkkey(unsigned bits, unsigned idx) {
    return ((unsigned long long)bits << 32) | (unsigned long long)(~idx);
}

// Pass 1: per-slab (32 rows) exact top-64 peaks, atomic-free capture.
// R10: two quads (different rows) per iteration -> 10 independent global
// loads in flight, 8 iterations instead of 16 (2x MLP, same traffic).
__global__ __launch_bounds__(256) void peaks_slab_kernel(
    const float* __restrict__ hm_all,
    unsigned long long* __restrict__ candWs, unsigned* __restrict__ cntWs)
{
    const int slab = blockIdx.x;
    const int map  = blockIdx.y;
    const float* __restrict__ hm = hm_all + (size_t)map * NPIX;
    const int r0 = slab * SLAB_ROWS;
    const int tid = threadIdx.x;
    const int wid = tid >> 6, lane = tid & 63;

    __shared__ unsigned long long allK[4 * SEGCAP];
    __shared__ unsigned long long selK[SELCAP];
    __shared__ unsigned long long topK[KTOP];
    __shared__ unsigned hist[NHIST];
    __shared__ unsigned segCnt[4], pcnt4[4];
    __shared__ unsigned s_sel, s_thr, s_fb, s_msel, s_total, s_captured;

    for (int i = tid; i < NHIST; i += 256) hist[i] = 0u;
    if (tid == 0) { s_sel = 0u; s_fb = 0u; }
    if (tid < KTOP) topK[tid] = 0ull;
    __syncthreads();

    const unsigned long long laneBelow = (1ull << lane) - 1ull;
    unsigned ccnt = 0;   // captured count (wave-uniform)
    unsigned pcnt = 0;   // true peak count (wave-uniform)
    const unsigned wbase = (unsigned)wid * SEGCAP;

    // scan: 2 quads per thread per iteration (rows r and r+2), all loads
    // independent; ballot compaction, zero same-address atomics.
    for (int c = tid; c < SLAB_ROWS * 128; c += 512) {
        const int c2 = c + 256;
        const int row1 = r0 + (c >> 7),  xc1 = (c & 127) << 2;
        const int row2 = r0 + (c2 >> 7), xc2 = (c2 & 127) << 2;
        const float* rp1 = hm + row1 * WW + xc1;
        const float* rp2 = hm + row2 * WW + xc2;

        float4 cur1 = *(const float4*)rp1;
        float4 up1  = (row1 > 0)      ? *(const float4*)(rp1 - WW) : make_float4(0,0,0,0);
        float4 dn1  = *(const float4*)(rp1 + WW);              // row1 <= r0+29 < 511
        float  lf1  = (xc1 > 0)      ? rp1[-1] : 0.0f;
        float  rt1  = (xc1 < WW - 4) ? rp1[4]  : 0.0f;
        float4 cur2 = *(const float4*)rp2;
        float4 up2  = *(const float4*)(rp2 - WW);              // row2 >= 2
        float4 dn2  = (row2 < HH - 1) ? *(const float4*)(rp2 + WW) : make_float4(0,0,0,0);
        float  lf2  = (xc2 > 0)      ? rp2[-1] : 0.0f;
        float  rt2  = (xc2 < WW - 4) ? rp2[4]  : 0.0f;

#define PROC_QUAD(CUR, UP, DN, LF, RT, ROW, XC)                                  \
        {                                                                        \
            float V[4] = {CUR.x, CUR.y, CUR.z, CUR.w};                           \
            float L[4] = {LF, CUR.x, CUR.y, CUR.z};                              \
            float R[4] = {CUR.y, CUR.z, CUR.w, RT};                              \
            float U[4] = {UP.x, UP.y, UP.z, UP.w};                               \
            float D[4] = {DN.x, DN.y, DN.z, DN.w};                               \
            _Pragma("unroll")                                                    \
            for (int k = 0; k < 4; k++) {                                        \
                float v = V[k];                                                  \
                bool pk = (v >= 0.1f) &&                                         \
                          (R[k] < 0.1f || v > R[k]) && (L[k] < 0.1f || v > L[k]) && \
                          (D[k] < 0.1f || v > D[k]) && (U[k] < 0.1f || v > U[k]);\
                unsigned bits = __float_as_uint(v);                              \
                bool cap = pk && (bits >= T0BITS);                               \
                unsigned long long pmask = __ballot(pk);                         \
                unsigned long long cmask = __ballot(cap);                        \
                if (cap) {                                                       \
                    unsigned pos = ccnt + (unsigned)__popcll(cmask & laneBelow); \
                    if (pos < SEGCAP)                                            \
                        allK[wbase + pos] = mkkey(bits, (unsigned)((ROW) * WW + (XC) + k)); \
                    else                                                         \
                        s_fb = 1u;                                               \
                }                                                                \
                ccnt += (unsigned)__popcll(cmask);                               \
                pcnt += (unsigned)__popcll(pmask);                               \
            }                                                                    \
        }
        PROC_QUAD(cur1, up1, dn1, lf1, rt1, row1, xc1)
        PROC_QUAD(cur2, up2, dn2, lf2, rt2, row2, xc2)
#undef PROC_QUAD
    }
    if (lane == 0) {
        segCnt[wid] = ccnt < SEGCAP ? ccnt : SEGCAP;
        pcnt4[wid] = pcnt;
    }
    __syncthreads();

    if (tid == 0) {
        unsigned total = pcnt4[0] + pcnt4[1] + pcnt4[2] + pcnt4[3];
        unsigned captured = segCnt[0] + segCnt[1] + segCnt[2] + segCnt[3];
        s_total = total;
        s_captured = captured;
        if (captured < (unsigned)KTOP && captured < total) s_fb = 1u;
        cntWs[map * NS + slab] = total;
    }
    __syncthreads();

    if (s_fb == 0u) {
        const unsigned captured = s_captured;
        for (int w = 0; w < 4; w++) {
            unsigned n = segCnt[w];
            for (unsigned i = tid; i < n; i += 256) {
                unsigned bits = (unsigned)(allK[w * SEGCAP + i] >> 32);
                unsigned b = (bits - T0BITS) >> 13;
                if (b >= NHIST) b = NHIST - 1;
                atomicAdd(&hist[b], 1u);
            }
        }
        __syncthreads();
        if (tid == 0) {
            unsigned thrBits, msel;
            if (captured < (unsigned)KTOP) {
                thrBits = T0BITS; msel = captured;
            } else {
                unsigned acc = 0; int b = NHIST - 1;
                for (; b >= 0; b--) {
                    acc += hist[b];
                    if (acc >= (unsigned)KTOP) break;
                }
                thrBits = T0BITS + ((unsigned)b << 13);
                msel = acc;
            }
            s_thr = thrBits;
            s_msel = msel;
            if (msel > (unsigned)SELCAP) s_fb = 1u;
        }
        __syncthreads();
    }

    if (s_fb == 0u) {
        const unsigned thrBits = s_thr;
        for (int w = 0; w < 4; w++) {
            unsigned n = segCnt[w];
            for (unsigned i = tid; i < n; i += 256) {
                unsigned long long k = allK[w * SEGCAP + i];
                if ((unsigned)(k >> 32) >= thrBits) {
                    unsigned p = atomicAdd(&s_sel, 1u);
                    selK[p] = k;
                }
            }
        }
        __syncthreads();
        int m = (int)s_sel;
        for (int i = tid; i < m; i += 256) {
            unsigned long long ki = selK[i];
            int rank = 0;
            for (int j = 0; j < m; j++) rank += (int)(selK[j] > ki);
            if (rank < KTOP) topK[rank] = ki;
        }
        __syncthreads();
    } else {
        // exact serial fallback (unreachable for benchmark data)
        if (tid == 0) {
            for (int t = 0; t < KTOP; t++) topK[t] = 0ull;
            unsigned total = 0;
            for (int p = 0; p < SLAB_ROWS * WW; p++) {
                int row = r0 + (p >> 9), x = p & 511;
                float v = hm[row * WW + x];
                if (v < 0.1f) continue;
                float R_ = (x < WW - 1)  ? hm[row * WW + x + 1] : 0.0f;
                float L_ = (x > 0)       ? hm[row * WW + x - 1] : 0.0f;
                float U_ = (row > 0)     ? hm[(row - 1) * WW + x] : 0.0f;
                float D_ = (row < HH-1)  ? hm[(row + 1) * WW + x] : 0.0f;
                bool pk = (R_ < 0.1f || v > R_) && (L_ < 0.1f || v > L_) &&
                          (D_ < 0.1f || v > D_) && (U_ < 0.1f || v > U_);
                if (pk) {
                    total++;
                    unsigned long long key = mkkey(__float_as_uint(v),
                                                   (unsigned)(row * WW + x));
                    if (key > topK[KTOP - 1]) {
                        int t = KTOP - 1;
                        while (t > 0 && topK[t - 1] < key) { topK[t] = topK[t - 1]; t--; }
                        topK[t] = key;
                    }
                }
            }
            cntWs[map * NS + slab] = total;
        }
        __syncthreads();
    }

    if (tid < KTOP)
        candWs[(size_t)(map * NS + slab) * KTOP + tid] = topK[tid];
}

// Pass 2 (R4 version): per-map merge of 16x64 candidates -> exact top-64,
// x-sort, NMS, write.
__global__ __launch_bounds__(1024) void merge_kernel(
    const float* __restrict__ hm_all,
    const unsigned long long* __restrict__ candWs, const unsigned* __restrict__ cntWs,
    float* __restrict__ coords, float* __restrict__ ss, float* __restrict__ ks)
{
    const int map = blockIdx.x;
    const int tid = threadIdx.x;

    __shared__ unsigned long long cK[NS * KTOP];
    __shared__ int sx[KTOP], sy[KTOP], svalid[KTOP];
    __shared__ float sv[KTOP];
    __shared__ int ox[KTOP], oyv[KTOP], oval[KTOP];
    __shared__ float osc[KTOP];
    __shared__ unsigned s_total;

    cK[tid] = candWs[(size_t)map * NS * KTOP + tid];
    if (tid == 0) {
        unsigned t = 0;
        for (int s = 0; s < NS; s++) t += cntWs[map * NS + s];
        s_total = t;
    }
    if (tid < KTOP) svalid[tid] = 0;
    __syncthreads();
    const unsigned total = s_total;

    {
        unsigned long long ki = cK[tid];
        if (ki != 0ull) {
            int rank = 0;
            for (int j = 0; j < NS * KTOP; j++) rank += (int)(cK[j] > ki);
            if (rank < KTOP) {
                unsigned ii = ~(unsigned)ki;
                sx[rank] = (int)(ii & 511u);
                sy[rank] = (int)(ii >> 9);
                sv[rank] = __uint_as_float((unsigned)(ki >> 32));
                svalid[rank] = 1;
            }
        }
    }
    __syncthreads();

    // Filler (only when a map has <64 peaks): smallest-index non-peak pixels.
    if (total < (unsigned)KTOP && tid == 0) {
        const float* hm = hm_all + (size_t)map * NPIX;
        auto tval = [&](int y, int x) -> float {
            if ((unsigned)x >= (unsigned)WW || (unsigned)y >= (unsigned)HH) return 0.0f;
            float v = hm[y * WW + x];
            return v < 0.1f ? 0.0f : v;
        };
        int cnt = (int)total;
        for (int p = 0; p < NPIX && cnt < KTOP; p++) {
            float v = hm[p];
            float tv = v < 0.1f ? 0.0f : v;
            int y = p >> 9, x = p & 511;
            bool pk = (tv > tval(y, x + 1)) && (tv > tval(y, x - 1)) &&
                      (tv > tval(y + 1, x)) && (tv > tval(y - 1, x));
            if (!pk) { sx[cnt] = x; sy[cnt] = y; sv[cnt] = tv; svalid[cnt] = 0; cnt++; }
        }
    }
    __syncthreads();

    // Stable sort by (x asc, rank asc); invalid keyed at W+1
    if (tid < KTOP) {
        int xk = svalid[tid] ? sx[tid] : (WW + 1);
        int fpos = 0;
        for (int t = 0; t < KTOP; t++) {
            int xkt = svalid[t] ? sx[t] : (WW + 1);
            fpos += (int)((xkt < xk) || (xkt == xk && t < tid));
        }
        ox[fpos] = sx[tid]; oyv[fpos] = sy[tid]; osc[fpos] = sv[tid]; oval[fpos] = svalid[tid];
    }
    __syncthreads();

    if (tid < KTOP) {
        int x = ox[tid], y = oyv[tid];
        float sc = osc[tid];
        int valid = oval[tid];
        int keep = valid;
        for (int i = 0; i < KTOP; i++) {
            int ki = __shfl(keep, i);
            int xi = __shfl(x, i);
            int yi = __shfl(y, i);
            if (ki && tid > i) {
                int ddx = x - xi, ddy = y - yi;
                if (ddx * ddx + ddy * ddy < 36) keep = 0;
            }
        }
        size_t base = (size_t)map * KTOP + tid;
        coords[base * 2 + 0] = 2.0f * (float)x;
        coords[base * 2 + 1] = 2.0f * (float)y;
        ss[base] = sc;
        ks[base] = keep ? 1.0f : 0.0f;
    }
}

// Limbs (R4 version: XCD swizzle + early-exit; high occupancy).
__global__ __launch_bounds__(256) void limbs_kernel(
    const float* __restrict__ paf_all,
    const float* __restrict__ coords, const float* __restrict__ ss, const float* __restrict__ ks,
    float* __restrict__ conn, float* __restrict__ cvalid)
{
    const int B = blockIdx.x;
    const int xcd = B & 7;
    const int seq = B >> 3;               // 0..303
    const int bl  = xcd * 19 + (seq >> 4);// b*19 + l
    const int q   = seq & 15;
    const int b = bl / 19, l = bl % 19;
    const int tid = threadIdx.x;

    __shared__ float axs[64], ays[64], sas[64];
    __shared__ float bxs[64], bys[64], sbs[64];
    __shared__ int kas[64], kbs[64];

    const int cA = KPT_A[l], cB = KPT_B[l];
    if (tid < 64) {
        size_t ia = (size_t)(b * 19 + cA) * 64 + tid;
        axs[tid] = coords[ia * 2]     * 0.5f;
        ays[tid] = coords[ia * 2 + 1] * 0.5f;
        sas[tid] = ss[ia];
        kas[tid] = ks[ia] > 0.5f;
    } else if (tid < 128) {
        int t = tid - 64;
        size_t ib = (size_t)(b * 19 + cB) * 64 + t;
        bxs[t] = coords[ib * 2]     * 0.5f;
        bys[t] = coords[ib * 2 + 1] * 0.5f;
        sbs[t] = ss[ib];
        kbs[t] = ks[ib] > 0.5f;
    }
    __syncthreads();

    const float* __restrict__ pafx = paf_all + ((size_t)b * 38 + PAF_X[l]) * NPIX;
    const float* __restrict__ pafy = paf_all + ((size_t)b * 38 + PAF_Y[l]) * NPIX;

    const int pair = q * 256 + tid;
    const int i = pair >> 6, j = pair & 63;

    float score = 0.0f, cval = 0.0f;
    if (kas[i] && kbs[j]) {
        float ax = axs[i], ay = ays[i];
        float bx = bxs[j], by = bys[j];
        float dx = bx - ax, dy = by - ay;
        float norm = sqrtf(__fadd_rn(__fmul_rn(dx, dx), __fmul_rn(dy, dy)));
        float safe = fmaxf(norm, 1e-6f);
        float ux = dx / safe, uy = dy / safe;

        int npass = 0, fails = 0;
        float ssum = 0.0f;
        // Early exit after 2nd failing sample: npass>=9 then impossible, and
        // every output is exactly 0 in that case — bit-identical shortcut.
#define SAMPLE(TK)                                                              \
        {                                                                       \
            float pxf = __fadd_rn(ax, __fmul_rn((TK), dx));                     \
            float pyf = __fadd_rn(ay, __fmul_rn((TK), dy));                     \
            int px = (int)rintf(pxf); px = px < 0 ? 0 : (px > WW - 1 ? WW - 1 : px); \
            int py = (int)rintf(pyf); py = py < 0 ? 0 : (py > HH - 1 ? HH - 1 : py); \
            int off = py * WW + px;                                             \
            float sc = __fadd_rn(__fmul_rn(ux, pafx[off]), __fmul_rn(uy, pafy[off])); \
            if (sc > 0.05f) { npass++; ssum = __fadd_rn(ssum, sc); }            \
            else if (++fails == 2) goto reject;                                 \
        }
        SAMPLE(0.0f)
        SAMPLE(1.0f / 9.0f)
        SAMPLE(2.0f / 9.0f)
        SAMPLE(3.0f / 9.0f)
        SAMPLE(4.0f / 9.0f)
        SAMPLE(5.0f / 9.0f)
        SAMPLE(6.0f / 9.0f)
        SAMPLE(7.0f / 9.0f)
        SAMPLE(8.0f / 9.0f)
        SAMPLE(1.0f)
#undef SAMPLE
        {
            float ratio = (npass > 0) ? (ssum / (float)npass) : 0.0f;
            float mpen = fminf(__fsub_rn(256.0f / safe, 1.0f), 0.0f);
            ratio = __fadd_rn(ratio, mpen);
            bool valid = (ratio > 0.0f) && (npass >= 9) && (norm > 0.0f);
            if (valid) {
                score = __fadd_rn(__fadd_rn(ratio, sas[i]), sbs[j]);
                cval = 1.0f;
            }
        }
reject: ;
    }

    size_t o = ((size_t)bl * 64 + i) * 64 + j;
    conn[o] = score;
    cvalid[o] = cval;
}

extern "C" void kernel_launch(void* const* d_in, const int* in_sizes, int n_in,
                              void* d_out, int out_size, void* d_ws, size_t ws_size,
                              hipStream_t stream) {
    const float* hm  = (const float*)d_in[0];
    const float* paf = (const float*)d_in[1];
    float* out = (float*)d_out;

    // Output layout (flat, return order): coords, ss, ks, conn, cvalid
    float* coords = out;                 // 8*19*64*2 = 19456
    float* ss     = out + 19456;         // 8*19*64   = 9728
    float* ks     = out + 29184;         // 8*19*64   = 9728
    float* conn   = out + 38912;         // 8*19*64*64 = 622592
    float* cvalid = out + 661504;        // 8*19*64*64 = 622592

    // Scratch in d_ws: candWs 152*16*64 u64 + cntWs.
    unsigned long long* candWs = (unsigned long long*)d_ws;
    unsigned* cntWs = (unsigned*)((char*)d_ws + (size_t)NMAPS * NS * KTOP * 8);

    dim3 gA(NS, NMAPS);
    peaks_slab_kernel<<<gA, 256, 0, stream>>>(hm, candWs, cntWs);
    merge_kernel<<<NMAPS, 1024, 0, stream>>>(hm, candWs, cntWs, coords, ss, ks);
    limbs_kernel<<<NMAPS * 16, 256, 0, stream>>>(paf, coords, ss, ks, conn, cvalid);
}